// Round 15
// baseline (167.819 us; speedup 1.0000x reference)
//
#include <hip/hip_runtime.h>
#include <math.h>

// Problem constants (match reference)
#define BATCH 4
#define LSEQ  4096
#define DCH   512
#define NST   16
#define DBLK  8                    // d-channels per block
#define TCH   32                   // chunk length along L
#define CCH   (LSEQ / TCH)         // 128 chunks
#define TPB   (DBLK * CCH)         // 1024 threads per block
#define NCHAIN (DBLK * NST)        // 128 (d,n) chains per block
#define CSTR  (NCHAIN + 4)         // 132: all LDS accesses <=2-way
#define SEG   16                   // chunks per P2 segment
#define NSEG  (CCH / SEG)          // 8 segments

// MODE 0: x loads only                (out = ws, keep-alive sum)
// MODE 1: + P1 scan + P2 scan + entry (out = ws)
// MODE 2: + P3 replay + dot, y summed (out = ws; no y stores)
// MODE 3: full real kernel            (out = y)  == R13 behavior
template<int MODE, int REP>
__global__ __launch_bounds__(TPB) void mamba_probe(
    const float* __restrict__ x, const float* __restrict__ A,
    const float* __restrict__ Bm, const float* __restrict__ delta,
    float* __restrict__ out)
{
    __shared__ float v[CCH * CSTR];      // 67.6 KB
    __shared__ float aT[NCHAIN];
    __shared__ float tot[NSEG * NCHAIN];

    const int lb   = (blockIdx.x & 7) * 32 + (blockIdx.x >> 3);  // XCD swizzle
    const int b    = lb >> 6;
    const int dgrp = lb & 63;
    const int d0   = dgrp * DBLK;

    const int tid = threadIdx.x;
    const int d   = tid & (DBLK - 1);
    const int c   = tid >> 3;

    const int dg   = d0 + d;
    const float dl = delta[dg];

    float dA[NST];
    const float4* Arow = (const float4*)(A + dg * NST);
#pragma unroll
    for (int q = 0; q < 4; ++q) {
        float4 a4 = Arow[q];
        dA[4*q+0] = expf(dl * a4.x);
        dA[4*q+1] = expf(dl * a4.y);
        dA[4*q+2] = expf(dl * a4.z);
        dA[4*q+3] = expf(dl * a4.w);
    }

    if (MODE >= 1 && c < NST) {
        float p = dA[c];
#pragma unroll
        for (int k = 0; k < 5; ++k) p *= p;   // ^32
        aT[c * DBLK + d] = p;
    }

    float dB[NST];
    if (MODE >= 2) {
        const float4* Brow = (const float4*)(Bm + dg * NST);
#pragma unroll
        for (int q = 0; q < 4; ++q) {
            float4 b4 = Brow[q];
            dB[4*q+0] = dl * b4.x;
            dB[4*q+1] = dl * b4.y;
            dB[4*q+2] = dl * b4.z;
            dB[4*q+3] = dl * b4.w;
        }
    }

    const float* xp = x + ((size_t)b * LSEQ + (size_t)c * TCH) * DCH + dg;
    float* yp = out + ((size_t)b * LSEQ + (size_t)c * TCH) * DCH + dg;
    float sum = 0.f;

#pragma unroll 1
    for (int r = 0; r < REP; ++r) {
        float xv[TCH];
#pragma unroll
        for (int t = 0; t < TCH; ++t)
            xv[t] = xp[(size_t)t * DCH];

        if (MODE == 0) {
#pragma unroll
            for (int t = 0; t < TCH; ++t) sum += xv[t];
        } else {
            // ---- P1: local g-scan ----
            float g[NST];
#pragma unroll
            for (int n = 0; n < NST; ++n) g[n] = 0.f;
#pragma unroll
            for (int t = 0; t < TCH; ++t) {
#pragma unroll
                for (int n = 0; n < NST; ++n)
                    g[n] = fmaf(g[n], dA[n], xv[t]);
            }
#pragma unroll
            for (int n = 0; n < NST; ++n)
                v[c * CSTR + (n * DBLK + d)] = g[n];
#pragma unroll
            for (int t = 0; t < TCH; ++t)
                asm volatile("" : "+v"(xv[t]));
            __syncthreads();

            // ---- P2: work-efficient scan ----
            {
                const int ch = tid & (NCHAIN - 1);
                const int s  = tid >> 7;
                const float aTc = aT[ch];
                float aT16 = aTc;
#pragma unroll
                for (int k = 0; k < 4; ++k) aT16 *= aT16;

                float sv[SEG];
#pragma unroll
                for (int i = 0; i < SEG; ++i)
                    sv[i] = v[(s * SEG + i) * CSTR + ch];
#pragma unroll
                for (int i = 1; i < SEG; ++i)
                    sv[i] = fmaf(sv[i-1], aTc, sv[i]);

                tot[s * NCHAIN + ch] = sv[SEG - 1];
                __syncthreads();

                float pfx = 0.f;
#pragma unroll
                for (int j = 0; j < NSEG - 1; ++j) {
                    float Tj = tot[j * NCHAIN + ch];
                    float np = fmaf(pfx, aT16, Tj);
                    pfx = (j < s) ? np : pfx;
                }

                float w = aTc;
#pragma unroll
                for (int i = 0; i < SEG; ++i) {
                    v[(s * SEG + i) * CSTR + ch] = fmaf(pfx, w, sv[i]);
                    w *= aTc;
                }
                __syncthreads();
            }

            // ---- entry state ----
            float g2[NST];
#pragma unroll
            for (int n = 0; n < NST; ++n) {
                int cm = (c > 0) ? (c - 1) : 0;
                float e = v[cm * CSTR + (n * DBLK + d)];
                g2[n] = (c > 0) ? e : 0.f;
            }

            if (MODE == 1) {
#pragma unroll
                for (int n = 0; n < NST; ++n) sum += g2[n];
                __syncthreads();              // next rep rewrites v
            } else {
                // ---- P3: replay + dot ----
#pragma unroll
                for (int t = 0; t < TCH; ++t) {
#pragma unroll
                    for (int n = 0; n < NST; ++n)
                        g2[n] = fmaf(g2[n], dA[n], xv[t]);
                    float a0 = 0.f, a1 = 0.f, a2 = 0.f, a3 = 0.f;
#pragma unroll
                    for (int n = 0; n < NST; n += 4) {
                        a0 = fmaf(g2[n+0], dB[n+0], a0);
                        a1 = fmaf(g2[n+1], dB[n+1], a1);
                        a2 = fmaf(g2[n+2], dB[n+2], a2);
                        a3 = fmaf(g2[n+3], dB[n+3], a3);
                    }
                    float yt = (a0 + a1) + (a2 + a3);
                    if (MODE == 2) sum += yt;
                    else           yp[(size_t)t * DCH] = yt;
                }
                if (MODE == 2) __syncthreads();   // next rep rewrites v
            }
        }
    }

    if (MODE != 3) {
        size_t gid = (size_t)blockIdx.x * TPB + tid;
        out[gid] = sum;   // keep-alive: everything feeds sum
    }
}

extern "C" void kernel_launch(void* const* d_in, const int* in_sizes, int n_in,
                              void* d_out, int out_size, void* d_ws, size_t ws_size,
                              hipStream_t stream) {
    const float* x     = (const float*)d_in[0];   // (B, L, D)
    const float* A     = (const float*)d_in[1];   // (D, N)
    const float* Bm    = (const float*)d_in[2];   // (D, N)
    const float* delta = (const float*)d_in[3];   // (D,)
    float*       y     = (float*)d_out;           // (B, L, D)
    float*       ws    = (float*)d_ws;

    const int nblocks = BATCH * (DCH / DBLK);     // 256 blocks

    // Diagnostic probes (write to ws; timings read from rocprof):
    mamba_probe<0, 24><<<nblocks, TPB, 0, stream>>>(x, A, Bm, delta, ws);
    mamba_probe<1, 6 ><<<nblocks, TPB, 0, stream>>>(x, A, Bm, delta, ws);
    mamba_probe<2, 4 ><<<nblocks, TPB, 0, stream>>>(x, A, Bm, delta, ws);
    // Real kernel (identical to R13):
    mamba_probe<3, 1 ><<<nblocks, TPB, 0, stream>>>(x, A, Bm, delta, y);
}

// Round 16
// 25.276 us; speedup vs baseline: 6.6394x; 6.6394x over previous
//
#include <hip/hip_runtime.h>
#include <math.h>

// Problem constants (match reference)
#define BATCH 4
#define LSEQ  4096
#define DCH   512
#define NST   16
#define DBLK  8                    // d-channels per block (forced: 2048/DBLK=256 blocks)
#define TCH   64                   // chunk length along L (64 -> 64-deep load MLP)
#define CCH   (LSEQ / TCH)         // 64 chunks
#define TPB   (DBLK * CCH)         // 512 threads per block
#define NCHAIN (DBLK * NST)        // 128 (d,n) chains per block
#define CSTR  (NCHAIN + 4)         // 132: all LDS access patterns <=2-way (free)
#define SEG   16                   // chunks per P2 segment
#define NSEG  (CCH / SEG)          // 4 segments

// One block = (batch b, 8-channel slice), full L in-block, one launch.
// 512 thr = 8 waves/CU; bet: 64-deep per-thread load MLP + ILP-16 chains
// beats R13's 16 shallow waves. __launch_bounds__(512,1) lifts the VGPR cap
// to 1-wave/EU budget so xv[64]+state (~130 live) does NOT spill (R7's bug).
// g-space recurrence: g = g*dA + x;  y = dot(g, dB).
// LDS v layout: v[chunk][chain], chain = n*DBLK + d, stride CSTR=132.
__global__ __launch_bounds__(TPB, 1) void mamba_one(
    const float* __restrict__ x, const float* __restrict__ A,
    const float* __restrict__ Bm, const float* __restrict__ delta,
    float* __restrict__ y)
{
    __shared__ float v[CCH * CSTR];      // 64 x 132 x 4B = 33.8 KB
    __shared__ float aT[NCHAIN];         // dA^TCH per chain
    __shared__ float tot[NSEG * NCHAIN]; // 4 x 128 x 4B = 2 KB

    // XCD swizzle: consecutive logical blocks (adjacent d-groups, shared
    // x cache lines) land on the same XCD's L2. 256 = 8 XCD x 32.
    const int lb   = (blockIdx.x & 7) * 32 + (blockIdx.x >> 3);  // 0..255
    const int b    = lb >> 6;                // 0..3
    const int dgrp = lb & 63;                // 0..63
    const int d0   = dgrp * DBLK;

    const int tid = threadIdx.x;
    const int d   = tid & (DBLK - 1);        // 0..7
    const int c   = tid >> 3;                // 0..63

    const int dg   = d0 + d;                 // global channel
    const float dl = delta[dg];

    float dA[NST], g[NST];
    const float4* Arow = (const float4*)(A + dg * NST);
#pragma unroll
    for (int q = 0; q < 4; ++q) {
        float4 a4 = Arow[q];
        dA[4*q+0] = expf(dl * a4.x);
        dA[4*q+1] = expf(dl * a4.y);
        dA[4*q+2] = expf(dl * a4.z);
        dA[4*q+3] = expf(dl * a4.w);
    }
#pragma unroll
    for (int n = 0; n < NST; ++n) g[n] = 0.f;

    // chain decay table: thread (d, c=n<16) publishes dA[n]^64 for chain n*8+d
    if (c < NST) {
        float p = dA[c];
#pragma unroll
        for (int k = 0; k < 6; ++k) p *= p;   // ^64 = ^TCH
        aT[c * DBLK + d] = p;
    }

    // ---- Phase 1: issue ALL 64 x loads (deep MLP), then g-scan; g -> v ----
    const float* xp = x + ((size_t)b * LSEQ + (size_t)c * TCH) * DCH + dg;
    float xv[TCH];
#pragma unroll
    for (int t = 0; t < TCH; ++t)
        xv[t] = xp[(size_t)t * DCH];      // 64 independent loads in flight

#pragma unroll
    for (int t = 0; t < TCH; ++t) {
#pragma unroll
        for (int n = 0; n < NST; ++n)
            g[n] = fmaf(g[n], dA[n], xv[t]);
    }
#pragma unroll
    for (int n = 0; n < NST; ++n)
        v[c * CSTR + (n * DBLK + d)] = g[n];

    // Pin xv in registers (before the barrier): opaque def prevents the
    // compiler from rematerializing the loads after P2 (R12/R13 evidence).
#pragma unroll
    for (int t = 0; t < TCH; ++t)
        asm volatile("" : "+v"(xv[t]));

    __syncthreads();

    // ---- Phase 2: work-efficient scan along c (128 chains x 64 chunks) ----
    {
        const int ch = tid & (NCHAIN - 1);   // chain (lane-consecutive)
        const int s  = tid >> 7;             // segment 0..3
        const float aTc = aT[ch];
        float aTS = aTc;
#pragma unroll
        for (int k = 0; k < 4; ++k) aTS *= aTS;   // (dA^64)^16

        // P2a: register inclusive scan of this 16-chunk segment
        float sv[SEG];
#pragma unroll
        for (int i = 0; i < SEG; ++i)
            sv[i] = v[(s * SEG + i) * CSTR + ch];
#pragma unroll
        for (int i = 1; i < SEG; ++i)
            sv[i] = fmaf(sv[i-1], aTc, sv[i]);

        tot[s * NCHAIN + ch] = sv[SEG - 1];
        __syncthreads();

        // P2b: carry-in = decayed scan of previous segment totals
        float pfx = 0.f;
#pragma unroll
        for (int j = 0; j < NSEG - 1; ++j) {
            float Tj = tot[j * NCHAIN + ch];
            float np = fmaf(pfx, aTS, Tj);
            pfx = (j < s) ? np : pfx;
        }

        // P2c: apply carry with powers of aTc, write back inclusive values
        float w = aTc;
#pragma unroll
        for (int i = 0; i < SEG; ++i) {
            v[(s * SEG + i) * CSTR + ch] = fmaf(pfx, w, sv[i]);
            w *= aTc;
        }
        __syncthreads();
    }

    // ---- Phase 3: entry = v[c-1]; replay from registers; y = dot(g, dB) ----
#pragma unroll
    for (int n = 0; n < NST; ++n) {
        int cm = (c > 0) ? (c - 1) : 0;
        float e = v[cm * CSTR + (n * DBLK + d)];
        g[n] = (c > 0) ? e : 0.f;
    }

    float dB[NST];
    const float4* Brow = (const float4*)(Bm + dg * NST);
#pragma unroll
    for (int q = 0; q < 4; ++q) {
        float4 b4 = Brow[q];
        dB[4*q+0] = dl * b4.x;
        dB[4*q+1] = dl * b4.y;
        dB[4*q+2] = dl * b4.z;
        dB[4*q+3] = dl * b4.w;
    }

    float* yp = y + ((size_t)b * LSEQ + (size_t)c * TCH) * DCH + dg;
#pragma unroll
    for (int t = 0; t < TCH; ++t) {
#pragma unroll
        for (int n = 0; n < NST; ++n)
            g[n] = fmaf(g[n], dA[n], xv[t]);
        float a0 = 0.f, a1 = 0.f, a2 = 0.f, a3 = 0.f;
#pragma unroll
        for (int n = 0; n < NST; n += 4) {
            a0 = fmaf(g[n+0], dB[n+0], a0);
            a1 = fmaf(g[n+1], dB[n+1], a1);
            a2 = fmaf(g[n+2], dB[n+2], a2);
            a3 = fmaf(g[n+3], dB[n+3], a3);
        }
        yp[(size_t)t * DCH] = (a0 + a1) + (a2 + a3);
    }
}

extern "C" void kernel_launch(void* const* d_in, const int* in_sizes, int n_in,
                              void* d_out, int out_size, void* d_ws, size_t ws_size,
                              hipStream_t stream) {
    const float* x     = (const float*)d_in[0];   // (B, L, D)
    const float* A     = (const float*)d_in[1];   // (D, N)
    const float* Bm    = (const float*)d_in[2];   // (D, N)
    const float* delta = (const float*)d_in[3];   // (D,)
    float*       y     = (float*)d_out;           // (B, L, D)

    const int nblocks = BATCH * (DCH / DBLK);     // 256 blocks, 1 per CU
    mamba_one<<<nblocks, TPB, 0, stream>>>(x, A, Bm, delta, y);
}